// Round 11
// baseline (173.065 us; speedup 1.0000x reference)
//
#include <hip/hip_runtime.h>
#include <math.h>

#define Bb 64
#define Ss 512
#define Hh 768
#define Ll 9
#define CCH 16      // CRF chunks per batch
#define TCH 32      // steps per chunk
#define KSTEPS 24   // 768 / 32
#define PF 4        // A-prefetch depth (float4 pairs)
#define SMEM_BYTES 51712

// LDS layout (bytes):
//   emis_s  :     0 .. 18432   (512*9 f32)         phases A+B
//   bpack   : 18432 .. 43008   (24*64 uint4)       phase A only
//   mkt_s   : 43008 .. 45056   (512 int)
//   trans_s : 45056 .. 45380   (81 f)
//   et_s    : 45380 .. 45704   (81 f)
//   erow_s  : 45704 .. 50888   (16*81 f)
//   rowmax_s: 50888 .. 51464   (16*9 f)
//   num_s   : 51464 .. 51468

typedef __attribute__((ext_vector_type(8))) short short8;   // 8 x bf16
typedef __attribute__((ext_vector_type(4))) float f32x4;

__device__ __forceinline__ ushort f2bf(float f) {           // RNE f32->bf16
    unsigned u = __float_as_uint(f);
    return (ushort)((u + 0x7FFFu + ((u >> 16) & 1u)) >> 16);
}

// block b == batch b: emissions (MFMA, into LDS) then CRF, all in-block.
__global__ __launch_bounds__(512) void k_fused(
    const float* __restrict__ hs, const float* __restrict__ W,
    const float* __restrict__ bvec, const float* __restrict__ cw,
    const float* __restrict__ startt, const float* __restrict__ endt,
    const float* __restrict__ trans, const int* __restrict__ labels,
    const int* __restrict__ attn, float* __restrict__ out)
{
    extern __shared__ char smem[];
    float* emis_s   = (float*)smem;
    uint4* bpack    = (uint4*)(smem + 18432);
    int*   mkt_s    = (int*)(smem + 43008);
    float* trans_s  = (float*)(smem + 45056);
    float* et_s     = (float*)(smem + 45380);
    float* erow_s   = (float*)(smem + 45704);
    float* rowmax_s = (float*)(smem + 50888);
    float* num_s    = (float*)(smem + 51464);

    const int b   = blockIdx.x;
    const int tid = threadIdx.x;

    // ---- stage masks/tags + transitions (tiny, overlaps with B-pack) ----
    {
        const int t = tid;   // 512 threads, 512 positions
        const int lab = labels[b * Ss + t];
        const int att = attn[b * Ss + t];
        const int tag = (lab == -100) ? 0 : lab;
        const int mk  = ((lab != -100) && (att == 1)) ? 1 : 0;
        mkt_s[t] = tag | (mk << 4);
    }
    if (tid < Ll * Ll) {
        const float tv = trans[tid];
        trans_s[tid] = tv;
        et_s[tid] = __expf(tv);
    }
    // ---- pack B fragments: bpack[k][lane] (uint4 = 8 bf16) ----
    for (int slot = tid; slot < KSTEPS * 64; slot += 512) {
        const int s = slot >> 6, l = slot & 63;
        const int col = l & 15, kg = l >> 4;
        ushort h[8];
#pragma unroll
        for (int j = 0; j < 8; ++j) {
            const int k = s * 32 + kg * 8 + j;
            h[j] = (col < Ll) ? f2bf(W[k * Ll + col]) : (ushort)0;
        }
        uint4 u;
        u.x = (unsigned)h[0] | ((unsigned)h[1] << 16);
        u.y = (unsigned)h[2] | ((unsigned)h[3] << 16);
        u.z = (unsigned)h[4] | ((unsigned)h[5] << 16);
        u.w = (unsigned)h[6] | ((unsigned)h[7] << 16);
        bpack[slot] = u;
    }
    __syncthreads();

    // ================= phase A: emissions into emis_s =================
    // wave w handles tiles {w, w+8, w+16, w+24}; flat 96-step loop, PF=4.
    {
        const int w    = tid >> 6;
        const int lane = tid & 63;
        const int col  = lane & 15, kg = lane >> 4;

        // address of (flat step s)'s A-chunk for this lane
        auto aaddr = [&](int s) -> const float* {
            const int ti = s / KSTEPS;           // 0..3
            const int k  = s - ti * KSTEPS;      // 0..23
            const int tile = w + ti * 8;
            return hs + (size_t)(b * Ss + tile * 16 + col) * Hh + kg * 8 + k * 32;
        };

        float4 pf0[PF], pf1[PF];
#pragma unroll
        for (int p = 0; p < PF; ++p) {
            const float* ap = aaddr(p);
            pf0[p] = *(const float4*)ap;
            pf1[p] = *(const float4*)(ap + 4);
        }

        f32x4 acc = {0.f, 0.f, 0.f, 0.f};
        for (int s = 0; s < 4 * KSTEPS; ++s) {
            const int slot = s & (PF - 1);
            const float4 a0 = pf0[slot], a1 = pf1[slot];
            if (s + PF < 4 * KSTEPS) {
                const float* ap = aaddr(s + PF);
                pf0[slot] = *(const float4*)ap;
                pf1[slot] = *(const float4*)(ap + 4);
            }
            short8 a;
            a[0] = (short)f2bf(a0.x); a[1] = (short)f2bf(a0.y);
            a[2] = (short)f2bf(a0.z); a[3] = (short)f2bf(a0.w);
            a[4] = (short)f2bf(a1.x); a[5] = (short)f2bf(a1.y);
            a[6] = (short)f2bf(a1.z); a[7] = (short)f2bf(a1.w);
            const int k = s % KSTEPS;
            const short8 bb = __builtin_bit_cast(short8, bpack[k * 64 + lane]);
            acc = __builtin_amdgcn_mfma_f32_16x16x32_bf16(a, bb, acc, 0, 0, 0);
            if (k == KSTEPS - 1) {
                // C/D: col = lane&15, row = kg*4 + j  [guide-verified]
                const int tile = w + (s / KSTEPS) * 8;
                if (col < Ll) {
                    const float cwv = cw[col], bv = bvec[col];
#pragma unroll
                    for (int j = 0; j < 4; ++j)
                        emis_s[(tile * 16 + kg * 4 + j) * Ll + col] =
                            (acc[j] + bv) * cwv;
                }
                acc = {0.f, 0.f, 0.f, 0.f};
            }
        }
    }
    __syncthreads();

    // ================= phase B: CRF =================
    // ---- chunk workers: tid < 144; row i of chunk c's 9x9 transfer matrix ----
    if (tid < CCH * Ll) {
        const int i = tid % Ll;
        const int c = tid / Ll;
        float et[Ll][Ll];
#pragma unroll
        for (int l = 0; l < Ll; ++l)
#pragma unroll
            for (int k = 0; k < Ll; ++k) et[l][k] = et_s[l * Ll + k];
        float vv[Ll];
#pragma unroll
        for (int l = 0; l < Ll; ++l) vv[l] = (l == i) ? 0.f : -1e30f;
        for (int s = (c == 0 ? 1 : 0); s < TCH; ++s) {
            const int t = c * TCH + s;
            const int mv = mkt_s[t];
            if (mv >> 4) {
                const float* e = emis_s + t * Ll;
                float m = vv[0];
#pragma unroll
                for (int l = 1; l < Ll; ++l) m = fmaxf(m, vv[l]);
                float p[Ll];
#pragma unroll
                for (int l = 0; l < Ll; ++l) p[l] = __expf(vv[l] - m);
                float nv[Ll];
#pragma unroll
                for (int k = 0; k < Ll; ++k) {
                    float sacc = 0.f;
#pragma unroll
                    for (int l = 0; l < Ll; ++l) sacc = fmaf(p[l], et[l][k], sacc);
                    nv[k] = m + __logf(sacc) + e[k];
                }
#pragma unroll
                for (int l = 0; l < Ll; ++l) vv[l] = nv[l];
            }
        }
        float m = vv[0];
#pragma unroll
        for (int l = 1; l < Ll; ++l) m = fmaxf(m, vv[l]);
        rowmax_s[c * Ll + i] = m;
#pragma unroll
        for (int l = 0; l < Ll; ++l)
            erow_s[(c * Ll + i) * Ll + l] = __expf(vv[l] - m);
    }

    // ---- numerator: wave 7 (tid 448..511) ----
    if (tid >= 448) {
        const int lane = tid - 448;
        float psum = 0.f;
        int pcnt = 0;
        for (int t = lane; t < Ss; t += 64) {
            const int mv  = mkt_s[t];
            const int tag = mv & 15;
            const bool mk = (mv >> 4) || (t == 0);
            if (t >= 1 && (mv >> 4)) {
                const int tagp = mkt_s[t - 1] & 15;
                psum += trans_s[tagp * Ll + tag] + emis_s[t * Ll + tag];
            }
            pcnt += mk ? 1 : 0;
        }
#pragma unroll
        for (int off = 32; off; off >>= 1) {
            psum += __shfl_xor(psum, off);
            pcnt += __shfl_xor(pcnt, off);
        }
        if (lane == 0) {
            const int tag0 = mkt_s[0] & 15;
            const int tagL = mkt_s[pcnt - 1] & 15;
            num_s[0] = startt[tag0] + emis_s[tag0] + psum + endt[tagL];
        }
    }
    __syncthreads();

    // ---- compose: lanes 0..8 of wave 0 (lane k owns column k) ----
    if (tid < Ll) {
        const int lane = tid;
        float sc[Ll];
#pragma unroll
        for (int l = 0; l < Ll; ++l) sc[l] = startt[l] + emis_s[l];
        for (int c = 0; c < CCH; ++c) {
            float u[Ll];
#pragma unroll
            for (int l = 0; l < Ll; ++l) u[l] = sc[l] + rowmax_s[c * Ll + l];
            float M = u[0];
#pragma unroll
            for (int l = 1; l < Ll; ++l) M = fmaxf(M, u[l]);
            float sacc = 0.f;
#pragma unroll
            for (int l = 0; l < Ll; ++l)
                sacc = fmaf(__expf(u[l] - M), erow_s[(c * Ll + l) * Ll + lane], sacc);
            const float ns = M + __logf(sacc);
#pragma unroll
            for (int l = 0; l < Ll; ++l) sc[l] = __shfl(ns, l);
        }
        float M2 = sc[0] + endt[0];
#pragma unroll
        for (int l = 1; l < Ll; ++l) M2 = fmaxf(M2, sc[l] + endt[l]);
        float s2 = 0.f;
#pragma unroll
        for (int l = 0; l < Ll; ++l) s2 += __expf(sc[l] + endt[l] - M2);
        if (lane == 0) {
            const float logz = M2 + __logf(s2);
            atomicAdd(out, -(num_s[0] - logz) * (1.f / Bb));
        }
    }
}

extern "C" void kernel_launch(void* const* d_in, const int* in_sizes, int n_in,
                              void* d_out, int out_size, void* d_ws, size_t ws_size,
                              hipStream_t stream)
{
    const float* hs     = (const float*)d_in[0];
    const float* W      = (const float*)d_in[1];
    const float* bvec   = (const float*)d_in[2];
    const float* cw     = (const float*)d_in[3];
    const float* startt = (const float*)d_in[4];
    const float* endt   = (const float*)d_in[5];
    const float* trans  = (const float*)d_in[6];
    const int*   labels = (const int*)d_in[7];
    const int*   attn   = (const int*)d_in[8];
    float* out = (float*)d_out;

    hipMemsetAsync(out, 0, sizeof(float), stream);
    hipLaunchKernelGGL(k_fused, dim3(Bb), dim3(512), SMEM_BYTES, stream,
                       hs, W, bvec, cw, startt, endt, trans, labels, attn, out);
}

// Round 12
// 102.426 us; speedup vs baseline: 1.6897x; 1.6897x over previous
//
#include <hip/hip_runtime.h>
#include <math.h>

#define Bb 64
#define Ss 512
#define Hh 768
#define Ll 9
#define CCH 16      // CRF chunks per batch
#define TCH 32      // steps per chunk
#define NROWS (Bb * Ss)       // 32768
#define NTILES (NROWS / 16)   // 2048
#define KSTEPS 24             // 768 / 32
#define NPROD 512             // producer blocks (4 waves x 1 tile each)
#define SMEM_BYTES 27648
// d_ws: emis f32[294912] | cnt int[64] | done int | wsum float  (control 264B)
#define CTRL_OFF 294912

typedef __attribute__((ext_vector_type(8))) short short8;   // 8 x bf16
typedef __attribute__((ext_vector_type(4))) float f32x4;

__device__ __forceinline__ ushort f2bf(float f) {           // RNE f32->bf16
    unsigned u = __float_as_uint(f);
    return (ushort)((u + 0x7FFFu + ((u >> 16) & 1u)) >> 16);
}

__global__ __launch_bounds__(256) void k_all(
    const float* __restrict__ hs, const float* __restrict__ W,
    const float* __restrict__ bvec, const float* __restrict__ cw,
    const float* __restrict__ startt, const float* __restrict__ endt,
    const float* __restrict__ trans, const int* __restrict__ labels,
    const int* __restrict__ attn, float* __restrict__ emis,
    int* __restrict__ cnt, float* __restrict__ out)
{
    extern __shared__ char smem[];
    const int tid = threadIdx.x;

    if (blockIdx.x < NPROD) {
        // ================= producer: MFMA emissions (R9-proven) =================
        uint4* bpack = (uint4*)smem;     // [KSTEPS][64], 24576 B
        for (int slot = tid; slot < KSTEPS * 64; slot += 256) {
            const int s = slot >> 6, l = slot & 63;
            const int col = l & 15, kg = l >> 4;
            ushort h[8];
#pragma unroll
            for (int j = 0; j < 8; ++j) {
                const int k = s * 32 + kg * 8 + j;
                h[j] = (col < Ll) ? f2bf(W[k * Ll + col]) : (ushort)0;
            }
            uint4 u;
            u.x = (unsigned)h[0] | ((unsigned)h[1] << 16);
            u.y = (unsigned)h[2] | ((unsigned)h[3] << 16);
            u.z = (unsigned)h[4] | ((unsigned)h[5] << 16);
            u.w = (unsigned)h[6] | ((unsigned)h[7] << 16);
            bpack[slot] = u;
        }
        __syncthreads();

        const int gwave = blockIdx.x * 4 + (tid >> 6);   // 1 tile per wave
        const int lane = tid & 63;
        const int col = lane & 15, kg = lane >> 4;
        const int row0 = gwave * 16;
        const float* ap = hs + (size_t)(row0 + col) * Hh + kg * 8;

        // depth-3 prefetch, FULLY UNROLLED loop (static slot indexing — rule #20)
        float4 c0[3], c1[3];
#pragma unroll
        for (int p = 0; p < 3; ++p) {
            c0[p] = *(const float4*)(ap + p * 32);
            c1[p] = *(const float4*)(ap + p * 32 + 4);
        }
        f32x4 acc = {0.f, 0.f, 0.f, 0.f};
#pragma unroll
        for (int t = 0; t < KSTEPS; ++t) {
            const int sl = t % 3;
            const float4 a0 = c0[sl], a1 = c1[sl];
            if (t + 3 < KSTEPS) {
                c0[sl] = *(const float4*)(ap + (t + 3) * 32);
                c1[sl] = *(const float4*)(ap + (t + 3) * 32 + 4);
            }
            short8 a;
            a[0] = (short)f2bf(a0.x); a[1] = (short)f2bf(a0.y);
            a[2] = (short)f2bf(a0.z); a[3] = (short)f2bf(a0.w);
            a[4] = (short)f2bf(a1.x); a[5] = (short)f2bf(a1.y);
            a[6] = (short)f2bf(a1.z); a[7] = (short)f2bf(a1.w);
            const short8 b = __builtin_bit_cast(short8, bpack[t * 64 + lane]);
            acc = __builtin_amdgcn_mfma_f32_16x16x32_bf16(a, b, acc, 0, 0, 0);
        }
        // C/D: col = lane&15, row = kg*4 + j  [guide-verified]
        if (col < Ll) {
            const float cwv = cw[col], bv = bvec[col];
#pragma unroll
            for (int j = 0; j < 4; ++j)
                emis[(size_t)(row0 + kg * 4 + j) * Ll + col] = (acc[j] + bv) * cwv;
        }
        __syncthreads();                         // drains stores (vmcnt 0)
        if (tid == 0) {
            __threadfence();                     // device-scope release of emis
            __hip_atomic_fetch_add(&cnt[blockIdx.x >> 3], 1,
                                   __ATOMIC_RELEASE, __HIP_MEMORY_SCOPE_AGENT);
        }
        return;
    }

    // ================= consumer: CRF for batch bc =================
    const int b = blockIdx.x - NPROD;
    int*   mkt_s    = (int*)smem;                  // 512 ints
    float* emis_s   = (float*)(smem + 2048);       // 4608 f
    float* trans_s  = (float*)(smem + 20480);      // 81 f
    float* et_s     = (float*)(smem + 20804);      // 81 f
    float* erow_s   = (float*)(smem + 21128);      // 16*81 f
    float* rowmax_s = (float*)(smem + 26312);      // 144 f
    float* num_s    = (float*)(smem + 26888);      // 1 f

    // stage label/mask + transitions while producers run
#pragma unroll
    for (int it = 0; it < 2; ++it) {
        const int t = tid + it * 256;
        const int lab = labels[b * Ss + t];
        const int att = attn[b * Ss + t];
        const int tag = (lab == -100) ? 0 : lab;
        const int mk  = ((lab != -100) && (att == 1)) ? 1 : 0;
        mkt_s[t] = tag | (mk << 4);
    }
    if (tid < Ll * Ll) {
        const float tv = trans[tid];
        trans_s[tid] = tv;
        et_s[tid] = __expf(tv);
    }
    // wait for this batch's 8 producer blocks (device-scope acquire)
    if (tid == 0) {
        while (__hip_atomic_load(&cnt[b], __ATOMIC_ACQUIRE,
                                 __HIP_MEMORY_SCOPE_AGENT) < 8)
            __builtin_amdgcn_s_sleep(8);
    }
    __syncthreads();
    {
        const float4* src = (const float4*)(emis + (size_t)b * Ss * Ll);
        float4* dst = (float4*)emis_s;
        for (int i = tid; i < (Ss * Ll) / 4; i += 256) dst[i] = src[i];
    }
    __syncthreads();

    // ---- chunk workers: tid < 144; row i of chunk c's 9x9 transfer matrix ----
    if (tid < CCH * Ll) {
        const int i = tid % Ll;
        const int c = tid / Ll;
        float et[Ll][Ll];
#pragma unroll
        for (int l = 0; l < Ll; ++l)
#pragma unroll
            for (int k = 0; k < Ll; ++k) et[l][k] = et_s[l * Ll + k];
        float vv[Ll];
#pragma unroll
        for (int l = 0; l < Ll; ++l) vv[l] = (l == i) ? 0.f : -1e30f;
        for (int s = (c == 0 ? 1 : 0); s < TCH; ++s) {
            const int t = c * TCH + s;
            const int mv = mkt_s[t];
            if (mv >> 4) {
                const float* e = emis_s + t * Ll;
                float m = vv[0];
#pragma unroll
                for (int l = 1; l < Ll; ++l) m = fmaxf(m, vv[l]);
                float p[Ll];
#pragma unroll
                for (int l = 0; l < Ll; ++l) p[l] = __expf(vv[l] - m);
                float nv[Ll];
#pragma unroll
                for (int k = 0; k < Ll; ++k) {
                    float sacc = 0.f;
#pragma unroll
                    for (int l = 0; l < Ll; ++l) sacc = fmaf(p[l], et[l][k], sacc);
                    nv[k] = m + __logf(sacc) + e[k];
                }
#pragma unroll
                for (int l = 0; l < Ll; ++l) vv[l] = nv[l];
            }
        }
        float m = vv[0];
#pragma unroll
        for (int l = 1; l < Ll; ++l) m = fmaxf(m, vv[l]);
        rowmax_s[c * Ll + i] = m;
#pragma unroll
        for (int l = 0; l < Ll; ++l)
            erow_s[(c * Ll + i) * Ll + l] = __expf(vv[l] - m);
    }

    // ---- numerator: wave 3 (tid 192..255) ----
    if (tid >= 192) {
        const int lane = tid - 192;
        float psum = 0.f;
        int pcnt = 0;
        for (int t = lane; t < Ss; t += 64) {
            const int mv  = mkt_s[t];
            const int tag = mv & 15;
            const bool mk = (mv >> 4) || (t == 0);
            if (t >= 1 && (mv >> 4)) {
                const int tagp = mkt_s[t - 1] & 15;
                psum += trans_s[tagp * Ll + tag] + emis_s[t * Ll + tag];
            }
            pcnt += mk ? 1 : 0;
        }
#pragma unroll
        for (int off = 32; off; off >>= 1) {
            psum += __shfl_xor(psum, off);
            pcnt += __shfl_xor(pcnt, off);
        }
        if (lane == 0) {
            const int tag0 = mkt_s[0] & 15;
            const int tagL = mkt_s[pcnt - 1] & 15;
            num_s[0] = startt[tag0] + emis_s[tag0] + psum + endt[tagL];
        }
    }
    __syncthreads();

    // ---- compose: lanes 0..8 of wave 0 (lane k owns column k) ----
    if (tid < Ll) {
        const int lane = tid;
        float sc[Ll];
#pragma unroll
        for (int l = 0; l < Ll; ++l) sc[l] = startt[l] + emis_s[l];
        for (int c = 0; c < CCH; ++c) {
            float u[Ll];
#pragma unroll
            for (int l = 0; l < Ll; ++l) u[l] = sc[l] + rowmax_s[c * Ll + l];
            float M = u[0];
#pragma unroll
            for (int l = 1; l < Ll; ++l) M = fmaxf(M, u[l]);
            float sacc = 0.f;
#pragma unroll
            for (int l = 0; l < Ll; ++l)
                sacc = fmaf(__expf(u[l] - M), erow_s[(c * Ll + l) * Ll + lane], sacc);
            const float ns = M + __logf(sacc);
#pragma unroll
            for (int l = 0; l < Ll; ++l) sc[l] = __shfl(ns, l);
        }
        float M2 = sc[0] + endt[0];
#pragma unroll
        for (int l = 1; l < Ll; ++l) M2 = fmaxf(M2, sc[l] + endt[l]);
        float s2 = 0.f;
#pragma unroll
        for (int l = 0; l < Ll; ++l) s2 += __expf(sc[l] + endt[l] - M2);
        if (lane == 0) {
            const float logz = M2 + __logf(s2);
            const float my = -(num_s[0] - logz) * (1.f / Bb);
            int* done   = cnt + Bb;
            float* wsum = (float*)(cnt + Bb + 1);
            atomicAdd(wsum, my);                 // device-scope
            const int d = __hip_atomic_fetch_add(done, 1, __ATOMIC_ACQ_REL,
                                                 __HIP_MEMORY_SCOPE_AGENT);
            if (d == Bb - 1) {                   // last consumer: all adds visible
                out[0] = __hip_atomic_load(wsum, __ATOMIC_ACQUIRE,
                                           __HIP_MEMORY_SCOPE_AGENT);
            }
        }
    }
}

extern "C" void kernel_launch(void* const* d_in, const int* in_sizes, int n_in,
                              void* d_out, int out_size, void* d_ws, size_t ws_size,
                              hipStream_t stream)
{
    const float* hs     = (const float*)d_in[0];
    const float* W      = (const float*)d_in[1];
    const float* bvec   = (const float*)d_in[2];
    const float* cw     = (const float*)d_in[3];
    const float* startt = (const float*)d_in[4];
    const float* endt   = (const float*)d_in[5];
    const float* trans  = (const float*)d_in[6];
    const int*   labels = (const int*)d_in[7];
    const int*   attn   = (const int*)d_in[8];
    float* out  = (float*)d_out;
    float* emis = (float*)d_ws;
    int*   cnt  = (int*)((float*)d_ws + CTRL_OFF);   // [64] cnt | done | wsum

    hipMemsetAsync(cnt, 0, (Bb + 2) * sizeof(int), stream);
    hipLaunchKernelGGL(k_all, dim3(NPROD + Bb), dim3(256), SMEM_BYTES, stream,
                       hs, W, bvec, cw, startt, endt, trans, labels, attn,
                       emis, cnt, out);
}

// Round 13
// 53.328 us; speedup vs baseline: 3.2453x; 1.9207x over previous
//
#include <hip/hip_runtime.h>
#include <math.h>

#define Bb 64
#define Ss 512
#define Hh 768
#define Ll 9
#define CCH 32      // CRF chunks per batch
#define TCH 16      // steps per chunk
#define NROWS (Bb * Ss)       // 32768
#define NTILES (NROWS / 16)   // 2048 == 256 blocks * 8 waves
#define KSTEPS 24             // 768 / 32
#define EMIS_SMEM 24576
#define CRF_SMEM  32656

typedef __attribute__((ext_vector_type(8))) short short8;   // 8 x bf16
typedef __attribute__((ext_vector_type(4))) float f32x4;

__device__ __forceinline__ ushort f2bf(float f) {           // RNE (W only)
    unsigned u = __float_as_uint(f);
    return (ushort)((u + 0x7FFFu + ((u >> 16) & 1u)) >> 16);
}

// ---------------- K1: MFMA emissions, wave-per-16-row-tile ----------------
__global__ __launch_bounds__(512) void k_emis(
    const float* __restrict__ hs, const float* __restrict__ W,
    const float* __restrict__ bvec, const float* __restrict__ cw,
    float* __restrict__ emis, float* __restrict__ out)
{
    extern __shared__ char smem[];
    uint4* bpack = (uint4*)smem;     // [KSTEPS][64] fragments
    const int tid = threadIdx.x;

    if (blockIdx.x == 0 && tid == 0) out[0] = 0.f;   // k_crf is stream-ordered after

    const int gwave = blockIdx.x * 8 + (tid >> 6);   // 8 waves/block, 1 tile/wave
    const int lane = tid & 63;
    const int col = lane & 15, kg = lane >> 4;
    const int row0 = gwave * 16;
    const float* ap = hs + (size_t)(row0 + col) * Hh + kg * 8;

    // ---- pre-issue depth-4 A prefetch BEFORE pack (hides pack+barrier) ----
    float4 c0[4], c1[4];
#pragma unroll
    for (int p = 0; p < 4; ++p) {
        c0[p] = *(const float4*)(ap + p * 32);
        c1[p] = *(const float4*)(ap + p * 32 + 4);
    }

    // ---- pack B fragments (once per block, 512 threads) ----
    for (int slot = tid; slot < KSTEPS * 64; slot += 512) {
        const int s = slot >> 6, l = slot & 63;
        const int bcol = l & 15, bkg = l >> 4;
        ushort h[8];
#pragma unroll
        for (int j = 0; j < 8; ++j) {
            const int k = s * 32 + bkg * 8 + j;
            h[j] = (bcol < Ll) ? f2bf(W[k * Ll + bcol]) : (ushort)0;
        }
        uint4 u;
        u.x = (unsigned)h[0] | ((unsigned)h[1] << 16);
        u.y = (unsigned)h[2] | ((unsigned)h[3] << 16);
        u.z = (unsigned)h[4] | ((unsigned)h[5] << 16);
        u.w = (unsigned)h[6] | ((unsigned)h[7] << 16);
        bpack[slot] = u;
    }
    __syncthreads();

    f32x4 acc = {0.f, 0.f, 0.f, 0.f};
#pragma unroll
    for (int t = 0; t < KSTEPS; ++t) {
        const int sl = t & 3;                 // static under full unroll (rule #20)
        const float4 a0 = c0[sl], a1 = c1[sl];
        if (t + 4 < KSTEPS) {
            c0[sl] = *(const float4*)(ap + (t + 4) * 32);
            c1[sl] = *(const float4*)(ap + (t + 4) * 32 + 4);
        }
        // truncation bf16 pair-pack: 2 ops per pair (vs ~6 RNE)
        const unsigned x0 = __float_as_uint(a0.x), x1 = __float_as_uint(a0.y);
        const unsigned x2 = __float_as_uint(a0.z), x3 = __float_as_uint(a0.w);
        const unsigned y0 = __float_as_uint(a1.x), y1 = __float_as_uint(a1.y);
        const unsigned y2 = __float_as_uint(a1.z), y3 = __float_as_uint(a1.w);
        uint4 au;
        au.x = (x1 & 0xFFFF0000u) | (x0 >> 16);
        au.y = (x3 & 0xFFFF0000u) | (x2 >> 16);
        au.z = (y1 & 0xFFFF0000u) | (y0 >> 16);
        au.w = (y3 & 0xFFFF0000u) | (y2 >> 16);
        const short8 a = __builtin_bit_cast(short8, au);
        const short8 b = __builtin_bit_cast(short8, bpack[t * 64 + lane]);
        acc = __builtin_amdgcn_mfma_f32_16x16x32_bf16(a, b, acc, 0, 0, 0);
    }
    // C/D: col = lane&15, row = kg*4 + j  [guide-verified]
    if (col < Ll) {
        const float cwv = cw[col], bv = bvec[col];
#pragma unroll
        for (int j = 0; j < 4; ++j)
            emis[(size_t)(row0 + kg * 4 + j) * Ll + col] = (acc[j] + bv) * cwv;
    }
}

// ---------------- K2: fused CRF per batch (512 threads) ----------------
__global__ __launch_bounds__(512) void k_crf(
    const float* __restrict__ emis, const int* __restrict__ labels,
    const int* __restrict__ attn, const float* __restrict__ trans,
    const float* __restrict__ startt, const float* __restrict__ endt,
    float* __restrict__ out)
{
    extern __shared__ char smem[];
    int*   mkt_s    = (int*)smem;                  //     0..2048  (512 int)
    float* emis_s   = (float*)(smem + 2048);       //  2048..20480 (4608 f)
    float* trans_s  = (float*)(smem + 20480);      // 81 f
    float* et_s     = (float*)(smem + 20804);      // 81 f
    float* erow_s   = (float*)(smem + 21128);      // 32*81 f
    float* rowmax_s = (float*)(smem + 31496);      // 32*9 f
    float* num_s    = (float*)(smem + 32648);      // 1 f

    const int b   = blockIdx.x;
    const int tid = threadIdx.x;

    {
        const int t = tid;   // 512 threads, 512 positions
        const int lab = labels[b * Ss + t];
        const int att = attn[b * Ss + t];
        const int tag = (lab == -100) ? 0 : lab;
        const int mk  = ((lab != -100) && (att == 1)) ? 1 : 0;
        mkt_s[t] = tag | (mk << 4);
    }
    {
        const float4* src = (const float4*)(emis + (size_t)b * Ss * Ll);
        float4* dst = (float4*)emis_s;
        for (int i = tid; i < (Ss * Ll) / 4; i += 512) dst[i] = src[i];
    }
    if (tid < Ll * Ll) {
        const float tv = trans[tid];
        trans_s[tid] = tv;
        et_s[tid] = __expf(tv);
    }
    __syncthreads();

    // ---- chunk workers: tid < 288; row i of chunk c's 9x9 transfer matrix ----
    if (tid < CCH * Ll) {
        const int i = tid % Ll;
        const int c = tid / Ll;
        float et[Ll][Ll];
#pragma unroll
        for (int l = 0; l < Ll; ++l)
#pragma unroll
            for (int k = 0; k < Ll; ++k) et[l][k] = et_s[l * Ll + k];
        float vv[Ll];
#pragma unroll
        for (int l = 0; l < Ll; ++l) vv[l] = (l == i) ? 0.f : -1e30f;
        for (int s = (c == 0 ? 1 : 0); s < TCH; ++s) {
            const int t = c * TCH + s;
            const int mv = mkt_s[t];
            if (mv >> 4) {
                const float* e = emis_s + t * Ll;
                float m = vv[0];
#pragma unroll
                for (int l = 1; l < Ll; ++l) m = fmaxf(m, vv[l]);
                float p[Ll];
#pragma unroll
                for (int l = 0; l < Ll; ++l) p[l] = __expf(vv[l] - m);
                float nv[Ll];
#pragma unroll
                for (int k = 0; k < Ll; ++k) {
                    float sacc = 0.f;
#pragma unroll
                    for (int l = 0; l < Ll; ++l) sacc = fmaf(p[l], et[l][k], sacc);
                    nv[k] = m + __logf(sacc) + e[k];
                }
#pragma unroll
                for (int l = 0; l < Ll; ++l) vv[l] = nv[l];
            }
        }
        float m = vv[0];
#pragma unroll
        for (int l = 1; l < Ll; ++l) m = fmaxf(m, vv[l]);
        rowmax_s[c * Ll + i] = m;
#pragma unroll
        for (int l = 0; l < Ll; ++l)
            erow_s[(c * Ll + i) * Ll + l] = __expf(vv[l] - m);
    }

    // ---- numerator: wave 7 (tid 448..511) ----
    if (tid >= 448) {
        const int lane = tid - 448;
        float psum = 0.f;
        int pcnt = 0;
        for (int t = lane; t < Ss; t += 64) {
            const int mv  = mkt_s[t];
            const int tag = mv & 15;
            const bool mk = (mv >> 4) || (t == 0);
            if (t >= 1 && (mv >> 4)) {
                const int tagp = mkt_s[t - 1] & 15;
                psum += trans_s[tagp * Ll + tag] + emis_s[t * Ll + tag];
            }
            pcnt += mk ? 1 : 0;
        }
#pragma unroll
        for (int off = 32; off; off >>= 1) {
            psum += __shfl_xor(psum, off);
            pcnt += __shfl_xor(pcnt, off);
        }
        if (lane == 0) {
            const int tag0 = mkt_s[0] & 15;
            const int tagL = mkt_s[pcnt - 1] & 15;
            num_s[0] = startt[tag0] + emis_s[tag0] + psum + endt[tagL];
        }
    }
    __syncthreads();

    // ---- compose: lanes 0..8 of wave 0 (lane k owns column k) ----
    if (tid < Ll) {
        const int lane = tid;
        float sc[Ll];
#pragma unroll
        for (int l = 0; l < Ll; ++l) sc[l] = startt[l] + emis_s[l];
        for (int c = 0; c < CCH; ++c) {
            float u[Ll];
#pragma unroll
            for (int l = 0; l < Ll; ++l) u[l] = sc[l] + rowmax_s[c * Ll + l];
            float M = u[0];
#pragma unroll
            for (int l = 1; l < Ll; ++l) M = fmaxf(M, u[l]);
            float sacc = 0.f;
#pragma unroll
            for (int l = 0; l < Ll; ++l)
                sacc = fmaf(__expf(u[l] - M), erow_s[(c * Ll + l) * Ll + lane], sacc);
            const float ns = M + __logf(sacc);
#pragma unroll
            for (int l = 0; l < Ll; ++l) sc[l] = __shfl(ns, l);
        }
        float M2 = sc[0] + endt[0];
#pragma unroll
        for (int l = 1; l < Ll; ++l) M2 = fmaxf(M2, sc[l] + endt[l]);
        float s2 = 0.f;
#pragma unroll
        for (int l = 0; l < Ll; ++l) s2 += __expf(sc[l] + endt[l] - M2);
        if (lane == 0) {
            const float logz = M2 + __logf(s2);
            atomicAdd(out, -(num_s[0] - logz) * (1.f / Bb));
        }
    }
}

extern "C" void kernel_launch(void* const* d_in, const int* in_sizes, int n_in,
                              void* d_out, int out_size, void* d_ws, size_t ws_size,
                              hipStream_t stream)
{
    const float* hs     = (const float*)d_in[0];
    const float* W      = (const float*)d_in[1];
    const float* bvec   = (const float*)d_in[2];
    const float* cw     = (const float*)d_in[3];
    const float* startt = (const float*)d_in[4];
    const float* endt   = (const float*)d_in[5];
    const float* trans  = (const float*)d_in[6];
    const int*   labels = (const int*)d_in[7];
    const int*   attn   = (const int*)d_in[8];
    float* out  = (float*)d_out;
    float* emis = (float*)d_ws;   // 64*512*9 floats

    hipLaunchKernelGGL(k_emis, dim3(NTILES / 8), dim3(512), EMIS_SMEM, stream,
                       hs, W, bvec, cw, emis, out);
    hipLaunchKernelGGL(k_crf, dim3(Bb), dim3(512), CRF_SMEM, stream,
                       emis, labels, attn, trans, startt, endt, out);
}

// Round 14
// 52.747 us; speedup vs baseline: 3.2810x; 1.0110x over previous
//
#include <hip/hip_runtime.h>
#include <math.h>

#define Bb 64
#define Ss 512
#define Hh 768
#define Ll 9
#define CCH 32      // CRF chunks per batch
#define TCH 16      // steps per chunk
#define NROWS (Bb * Ss)       // 32768
#define NTILES (NROWS / 16)   // 2048 tiles; 2 waves per tile (K-split)
#define KSTEPS 24             // 768 / 32
#define KHALF 12              // K-steps per wave
#define EMIS_SMEM 28672       // bpack 24576 + combine 4096
#define CRF_SMEM  32656

typedef __attribute__((ext_vector_type(8))) short short8;   // 8 x bf16
typedef __attribute__((ext_vector_type(4))) float f32x4;

__device__ __forceinline__ ushort f2bf(float f) {           // RNE (W only)
    unsigned u = __float_as_uint(f);
    return (ushort)((u + 0x7FFFu + ((u >> 16) & 1u)) >> 16);
}

// ---------------- K1: MFMA emissions, 2 waves per 16-row tile (K-split) ----------------
__global__ __launch_bounds__(512, 2) void k_emis(
    const float* __restrict__ hs, const float* __restrict__ W,
    const float* __restrict__ bvec, const float* __restrict__ cw,
    float* __restrict__ emis, float* __restrict__ out)
{
    extern __shared__ char smem[];
    uint4* bpack = (uint4*)smem;                 // [KSTEPS][64]
    float* comb  = (float*)(smem + 24576);       // [4][4*64] partial accs
    const int tid = threadIdx.x;

    if (blockIdx.x == 0 && tid == 0) out[0] = 0.f;   // k_crf is stream-ordered after

    const int wid  = tid >> 6;            // 0..7
    const int tl   = wid >> 1;            // local tile 0..3
    const int half = wid & 1;             // K-half
    const int lane = tid & 63;
    const int col = lane & 15, kg = lane >> 4;
    const int gtile = blockIdx.x * 4 + tl;
    const int row0 = gtile * 16;
    // this wave's A base: K-offset half*KHALF*32 floats
    const float* ap = hs + (size_t)(row0 + col) * Hh + kg * 8 + half * (KHALF * 32);

    // ---- pre-issue depth-4 A prefetch BEFORE pack (hides pack+barrier) ----
    float4 c0[4], c1[4];
#pragma unroll
    for (int p = 0; p < 4; ++p) {
        c0[p] = *(const float4*)(ap + p * 32);
        c1[p] = *(const float4*)(ap + p * 32 + 4);
    }

    // ---- pack B fragments (once per block, 512 threads, 3 slots each) ----
    for (int slot = tid; slot < KSTEPS * 64; slot += 512) {
        const int s = slot >> 6, l = slot & 63;
        const int bcol = l & 15, bkg = l >> 4;
        ushort h[8];
#pragma unroll
        for (int j = 0; j < 8; ++j) {
            const int k = s * 32 + bkg * 8 + j;
            h[j] = (bcol < Ll) ? f2bf(W[k * Ll + bcol]) : (ushort)0;
        }
        uint4 u;
        u.x = (unsigned)h[0] | ((unsigned)h[1] << 16);
        u.y = (unsigned)h[2] | ((unsigned)h[3] << 16);
        u.z = (unsigned)h[4] | ((unsigned)h[5] << 16);
        u.w = (unsigned)h[6] | ((unsigned)h[7] << 16);
        bpack[slot] = u;
    }
    __syncthreads();

    f32x4 acc = {0.f, 0.f, 0.f, 0.f};
#pragma unroll
    for (int t = 0; t < KHALF; ++t) {
        const int sl = t & 3;                 // static under full unroll
        const float4 a0 = c0[sl], a1 = c1[sl];
        if (t + 4 < KHALF) {
            c0[sl] = *(const float4*)(ap + (t + 4) * 32);
            c1[sl] = *(const float4*)(ap + (t + 4) * 32 + 4);
        }
        // truncation bf16 pair-pack (A only; W uses RNE)
        const unsigned x0 = __float_as_uint(a0.x), x1 = __float_as_uint(a0.y);
        const unsigned x2 = __float_as_uint(a0.z), x3 = __float_as_uint(a0.w);
        const unsigned y0 = __float_as_uint(a1.x), y1 = __float_as_uint(a1.y);
        const unsigned y2 = __float_as_uint(a1.z), y3 = __float_as_uint(a1.w);
        uint4 au;
        au.x = (x1 & 0xFFFF0000u) | (x0 >> 16);
        au.y = (x3 & 0xFFFF0000u) | (x2 >> 16);
        au.z = (y1 & 0xFFFF0000u) | (y0 >> 16);
        au.w = (y3 & 0xFFFF0000u) | (y2 >> 16);
        const short8 a = __builtin_bit_cast(short8, au);
        const short8 b = __builtin_bit_cast(short8,
                                            bpack[(half * KHALF + t) * 64 + lane]);
        acc = __builtin_amdgcn_mfma_f32_16x16x32_bf16(a, b, acc, 0, 0, 0);
    }

    // ---- combine K-halves via LDS (conflict-free: lane-contiguous) ----
    if (half == 1) {
#pragma unroll
        for (int j = 0; j < 4; ++j)
            comb[(tl * 4 + j) * 64 + lane] = acc[j];
    }
    __syncthreads();
    if (half == 0) {
#pragma unroll
        for (int j = 0; j < 4; ++j)
            acc[j] += comb[(tl * 4 + j) * 64 + lane];
        // C/D: col = lane&15, row = kg*4 + j  [guide-verified]
        if (col < Ll) {
            const float cwv = cw[col], bv = bvec[col];
#pragma unroll
            for (int j = 0; j < 4; ++j)
                emis[(size_t)(row0 + kg * 4 + j) * Ll + col] = (acc[j] + bv) * cwv;
        }
    }
}

// ---------------- K2: fused CRF per batch (512 threads) ----------------
__global__ __launch_bounds__(512) void k_crf(
    const float* __restrict__ emis, const int* __restrict__ labels,
    const int* __restrict__ attn, const float* __restrict__ trans,
    const float* __restrict__ startt, const float* __restrict__ endt,
    float* __restrict__ out)
{
    extern __shared__ char smem[];
    int*   mkt_s    = (int*)smem;                  // 512 int
    float* emis_s   = (float*)(smem + 2048);       // 4608 f
    float* trans_s  = (float*)(smem + 20480);      // 81 f
    float* et_s     = (float*)(smem + 20804);      // 81 f
    float* erow_s   = (float*)(smem + 21128);      // 32*81 f
    float* rowmax_s = (float*)(smem + 31496);      // 32*9 f
    float* num_s    = (float*)(smem + 32648);      // 1 f

    const int b   = blockIdx.x;
    const int tid = threadIdx.x;

    {
        const int t = tid;
        const int lab = labels[b * Ss + t];
        const int att = attn[b * Ss + t];
        const int tag = (lab == -100) ? 0 : lab;
        const int mk  = ((lab != -100) && (att == 1)) ? 1 : 0;
        mkt_s[t] = tag | (mk << 4);
    }
    {
        const float4* src = (const float4*)(emis + (size_t)b * Ss * Ll);
        float4* dst = (float4*)emis_s;
        for (int i = tid; i < (Ss * Ll) / 4; i += 512) dst[i] = src[i];
    }
    if (tid < Ll * Ll) {
        const float tv = trans[tid];
        trans_s[tid] = tv;
        et_s[tid] = __expf(tv);
    }
    __syncthreads();

    // ---- chunk workers: tid < 288; row i of chunk c's 9x9 transfer matrix ----
    if (tid < CCH * Ll) {
        const int i = tid % Ll;
        const int c = tid / Ll;
        float et[Ll][Ll];
#pragma unroll
        for (int l = 0; l < Ll; ++l)
#pragma unroll
            for (int k = 0; k < Ll; ++k) et[l][k] = et_s[l * Ll + k];
        float vv[Ll];
#pragma unroll
        for (int l = 0; l < Ll; ++l) vv[l] = (l == i) ? 0.f : -1e30f;
        for (int s = (c == 0 ? 1 : 0); s < TCH; ++s) {
            const int t = c * TCH + s;
            const int mv = mkt_s[t];
            if (mv >> 4) {
                const float* e = emis_s + t * Ll;
                float m = vv[0];
#pragma unroll
                for (int l = 1; l < Ll; ++l) m = fmaxf(m, vv[l]);
                float p[Ll];
#pragma unroll
                for (int l = 0; l < Ll; ++l) p[l] = __expf(vv[l] - m);
                float nv[Ll];
#pragma unroll
                for (int k = 0; k < Ll; ++k) {
                    float sacc = 0.f;
#pragma unroll
                    for (int l = 0; l < Ll; ++l) sacc = fmaf(p[l], et[l][k], sacc);
                    nv[k] = m + __logf(sacc) + e[k];
                }
#pragma unroll
                for (int l = 0; l < Ll; ++l) vv[l] = nv[l];
            }
        }
        float m = vv[0];
#pragma unroll
        for (int l = 1; l < Ll; ++l) m = fmaxf(m, vv[l]);
        rowmax_s[c * Ll + i] = m;
#pragma unroll
        for (int l = 0; l < Ll; ++l)
            erow_s[(c * Ll + i) * Ll + l] = __expf(vv[l] - m);
    }

    // ---- numerator: wave 7 (tid 448..511) ----
    if (tid >= 448) {
        const int lane = tid - 448;
        float psum = 0.f;
        int pcnt = 0;
        for (int t = lane; t < Ss; t += 64) {
            const int mv  = mkt_s[t];
            const int tag = mv & 15;
            const bool mk = (mv >> 4) || (t == 0);
            if (t >= 1 && (mv >> 4)) {
                const int tagp = mkt_s[t - 1] & 15;
                psum += trans_s[tagp * Ll + tag] + emis_s[t * Ll + tag];
            }
            pcnt += mk ? 1 : 0;
        }
#pragma unroll
        for (int off = 32; off; off >>= 1) {
            psum += __shfl_xor(psum, off);
            pcnt += __shfl_xor(pcnt, off);
        }
        if (lane == 0) {
            const int tag0 = mkt_s[0] & 15;
            const int tagL = mkt_s[pcnt - 1] & 15;
            num_s[0] = startt[tag0] + emis_s[tag0] + psum + endt[tagL];
        }
    }
    __syncthreads();

    // ---- compose: lanes 0..8 of wave 0 (lane k owns column k) ----
    if (tid < Ll) {
        const int lane = tid;
        float sc[Ll];
#pragma unroll
        for (int l = 0; l < Ll; ++l) sc[l] = startt[l] + emis_s[l];
        for (int c = 0; c < CCH; ++c) {
            float u[Ll];
#pragma unroll
            for (int l = 0; l < Ll; ++l) u[l] = sc[l] + rowmax_s[c * Ll + l];
            float M = u[0];
#pragma unroll
            for (int l = 1; l < Ll; ++l) M = fmaxf(M, u[l]);
            float sacc = 0.f;
#pragma unroll
            for (int l = 0; l < Ll; ++l)
                sacc = fmaf(__expf(u[l] - M), erow_s[(c * Ll + l) * Ll + lane], sacc);
            const float ns = M + __logf(sacc);
#pragma unroll
            for (int l = 0; l < Ll; ++l) sc[l] = __shfl(ns, l);
        }
        float M2 = sc[0] + endt[0];
#pragma unroll
        for (int l = 1; l < Ll; ++l) M2 = fmaxf(M2, sc[l] + endt[l]);
        float s2 = 0.f;
#pragma unroll
        for (int l = 0; l < Ll; ++l) s2 += __expf(sc[l] + endt[l] - M2);
        if (lane == 0) {
            const float logz = M2 + __logf(s2);
            atomicAdd(out, -(num_s[0] - logz) * (1.f / Bb));
        }
    }
}

extern "C" void kernel_launch(void* const* d_in, const int* in_sizes, int n_in,
                              void* d_out, int out_size, void* d_ws, size_t ws_size,
                              hipStream_t stream)
{
    const float* hs     = (const float*)d_in[0];
    const float* W      = (const float*)d_in[1];
    const float* bvec   = (const float*)d_in[2];
    const float* cw     = (const float*)d_in[3];
    const float* startt = (const float*)d_in[4];
    const float* endt   = (const float*)d_in[5];
    const float* trans  = (const float*)d_in[6];
    const int*   labels = (const int*)d_in[7];
    const int*   attn   = (const int*)d_in[8];
    float* out  = (float*)d_out;
    float* emis = (float*)d_ws;   // 64*512*9 floats

    hipLaunchKernelGGL(k_emis, dim3(NTILES / 4), dim3(512), EMIS_SMEM, stream,
                       hs, W, bvec, cw, emis, out);
    hipLaunchKernelGGL(k_crf, dim3(Bb), dim3(512), CRF_SMEM, stream,
                       emis, labels, attn, trans, startt, endt, out);
}